// Round 21
// baseline (85.453 us; speedup 1.0000x reference)
//
#include <hip/hip_runtime.h>
#include <math.h>

#define D_MODEL 4096
#define NEXP    64
#define NTOK    16384
#define NSL     4                  // K-slices; K/block = 1024
#define NCH     8                  // W-chunks per block (double-buffered)
#define KS      128                // K per LDS-resident W chunk
#define BMT     128                // tokens per block (8 waves x 16 tokens)

typedef __attribute__((ext_vector_type(8))) short  bf16x8;
typedef __attribute__((ext_vector_type(4))) float  f32x4;

__device__ __forceinline__ unsigned short f2bf_rn(float f) {
    union { float f; unsigned u; } v; v.f = f;
    unsigned r = v.u + 0x7fffu + ((v.u >> 16) & 1u);
    return (unsigned short)(r >> 16);
}
__device__ __forceinline__ float bf2f(unsigned short h) {
    union { unsigned u; float f; } v; v.u = ((unsigned)h) << 16;
    return v.f;
}
// split two floats into packed bf16 hi-word and lo-word (RNE both)
__device__ __forceinline__ void split2(float f0, float f1, unsigned& hw, unsigned& lw) {
    unsigned short h0 = f2bf_rn(f0), h1 = f2bf_rn(f1);
    unsigned short l0 = f2bf_rn(f0 - bf2f(h0)), l1 = f2bf_rn(f1 - bf2f(h1));
    hw = (unsigned)h0 | ((unsigned)h1 << 16);
    lw = (unsigned)l0 | ((unsigned)l1 << 16);
}
// pinned 16B global load (asm volatile: compiler cannot sink it to its use)
__device__ __forceinline__ void gload16(f32x4& r, const float* p) {
    asm volatile("global_load_dwordx4 %0, %1, off" : "=v"(r) : "v"(p));
}

#define WAITV_(n) asm volatile("s_waitcnt vmcnt(" #n ")" ::: "memory")
#define WAITV(n)  WAITV_(n)

// ---------------------------------------------------------------------------
// k0: split W into bf16 hi/lo halves; zero logits accumulator + counts tail.
// ---------------------------------------------------------------------------
__global__ __launch_bounds__(256)
void k0_prep(const float* __restrict__ W, unsigned short* __restrict__ ws,
             float* __restrict__ logits, float* __restrict__ out) {
    const int gid = blockIdx.x * 256 + threadIdx.x;
    if (blockIdx.x == 0 && threadIdx.x < NEXP)
        out[(size_t)2 * NTOK * NEXP + threadIdx.x] = 0.f;
    float4 z = make_float4(0.f, 0.f, 0.f, 0.f);
    float* lz = logits + (size_t)gid * 16;
#pragma unroll
    for (int k = 0; k < 4; ++k)
        *reinterpret_cast<float4*>(&lz[k * 4]) = z;
    int i = gid * 4;
    float4 v = *reinterpret_cast<const float4*>(&W[i]);
    unsigned short h[4], l[4];
    float f[4] = {v.x, v.y, v.z, v.w};
#pragma unroll
    for (int k = 0; k < 4; ++k) {
        h[k] = f2bf_rn(f[k]);
        l[k] = f2bf_rn(f[k] - bf2f(h[k]));
    }
    *reinterpret_cast<short4*>(&ws[i])                  = make_short4(h[0], h[1], h[2], h[3]);
    *reinterpret_cast<short4*>(&ws[NEXP * D_MODEL + i]) = make_short4(l[0], l[1], l[2], l[3]);
}

// ---------------------------------------------------------------------------
// k1: split-K GEMM partial — r19 exactly (83.1us validated best).
// 8 waves x 16 tokens x 64 experts, K=1024/block via 8 double-buffered
// KS=128 W chunks; W prefetch oldest-in-queue before x-prologue; pinned-asm
// x FIFO with counted vmcnt inside each chunk; __syncthreads() per chunk.
// ---------------------------------------------------------------------------
__global__ __launch_bounds__(512, 4)
void k1_gemm(const float* __restrict__ x, const unsigned short* __restrict__ wsplit,
             float* __restrict__ logits) {
    __shared__ uint4 whi[2][NEXP * 16];   // 2 x 16 KiB
    __shared__ uint4 wlo[2][NEXP * 16];   // 2 x 16 KiB

    const int tid = threadIdx.x;
    const int t0  = (blockIdx.x >> 2) * BMT;
    const int sp  = blockIdx.x & 3;    // slice -> K [sp*1024, sp*1024+1024)

    const int lane = tid & 63;
    const int rowl = lane & 15;
    const int grp  = lane >> 4;        // k-slot
    const int wtok = t0 + (tid >> 6) * 16;   // wave w -> 16-token strip

    // W staging geometry: thread covers (e,c) pairs p0=tid, p1=tid+512
    const int e0 = tid >> 4,          c0 = tid & 15;
    const int e1 = (tid + 512) >> 4,  c1 = tid & 15;   // (tid+512)&15 == tid&15
    const int cs0 = (c0 & 8) | ((c0 & 7) ^ (e0 & 7));
    const int cs1 = (c1 & 8) | ((c1 & 7) ^ (e1 & 7));

    f32x4 acc[4];
#pragma unroll
    for (int n = 0; n < 4; ++n)
        acc[n] = (f32x4){0.f, 0.f, 0.f, 0.f};

    // prologue: W chunk 0 -> buf 0 (the single serial W phase)
    {
        const int ks00 = sp * (NCH * KS);
        const unsigned short* s0 = wsplit + (size_t)e0 * D_MODEL + ks00 + c0 * 8;
        const unsigned short* s1 = wsplit + (size_t)e1 * D_MODEL + ks00 + c1 * 8;
        whi[0][e0 * 16 + cs0] = *reinterpret_cast<const uint4*>(s0);
        wlo[0][e0 * 16 + cs0] = *reinterpret_cast<const uint4*>(s0 + NEXP * D_MODEL);
        whi[0][e1 * 16 + cs1] = *reinterpret_cast<const uint4*>(s1);
        wlo[0][e1 * 16 + cs1] = *reinterpret_cast<const uint4*>(s1 + NEXP * D_MODEL);
    }
    __syncthreads();

// one pipeline step: wait iter-kb, split, re-issue regs for iter kb+2, MFMA
#define STEPX(kb, WN, c0r, c1r, DOI, BH, BL) do {                            \
    WAITV(WN);                                                               \
    __builtin_amdgcn_sched_barrier(0);                                       \
    union { bf16x8 v; unsigned u[4]; } ah, al;                               \
    split2(c0r.x, c0r.y, ah.u[0], al.u[0]);                                  \
    split2(c0r.z, c0r.w, ah.u[1], al.u[1]);                                  \
    split2(c1r.x, c1r.y, ah.u[2], al.u[2]);                                  \
    split2(c1r.z, c1r.w, ah.u[3], al.u[3]);                                  \
    if (DOI) {                                                               \
        gload16(c0r, xp0 + ((kb) + 2) * 32);                                 \
        gload16(c1r, xp0 + ((kb) + 2) * 32 + 4);                             \
    }                                                                        \
    const int c  = (kb) * 4 + grp;                                           \
    const int cs = (c & 8) | ((c & 7) ^ (rowl & 7));    /* e&7 == rowl&7 */  \
    _Pragma("unroll")                                                        \
    for (int n = 0; n < 4; ++n) {                                            \
        const int idx = (n * 16 + rowl) * 16 + cs;                           \
        bf16x8 bh = *reinterpret_cast<const bf16x8*>(&BH[idx]);              \
        bf16x8 bl = *reinterpret_cast<const bf16x8*>(&BL[idx]);              \
        acc[n] = __builtin_amdgcn_mfma_f32_16x16x32_bf16(ah.v, bh, acc[n], 0, 0, 0); \
        acc[n] = __builtin_amdgcn_mfma_f32_16x16x32_bf16(ah.v, bl, acc[n], 0, 0, 0); \
        acc[n] = __builtin_amdgcn_mfma_f32_16x16x32_bf16(al.v, bh, acc[n], 0, 0, 0); \
    }                                                                        \
} while (0)

#pragma unroll
    for (int ch = 0; ch < NCH; ++ch) {
        const int ks0 = sp * (NCH * KS) + ch * KS;

        // prefetch next W chunk into regs FIRST (oldest in vmcnt queue);
        // sched_barrier pins against sinking (r4 pathology)
        uint4 wh0, wl0, wh1, wl1;
        if (ch + 1 < NCH) {
            const unsigned short* s0 = wsplit + (size_t)e0 * D_MODEL + ks0 + KS + c0 * 8;
            const unsigned short* s1 = wsplit + (size_t)e1 * D_MODEL + ks0 + KS + c1 * 8;
            wh0 = *reinterpret_cast<const uint4*>(s0);
            wl0 = *reinterpret_cast<const uint4*>(s0 + NEXP * D_MODEL);
            wh1 = *reinterpret_cast<const uint4*>(s1);
            wl1 = *reinterpret_cast<const uint4*>(s1 + NEXP * D_MODEL);
        }
        __builtin_amdgcn_sched_barrier(0);

        const uint4* BH = &whi[ch & 1][0];
        const uint4* BL = &wlo[ch & 1][0];
        const float* xp0 = x + (size_t)(wtok + rowl) * D_MODEL + ks0 + grp * 8;

        // x prologue: pin iters 0 (A) and 1 (B) in flight
        f32x4 xA0, xA1, xB0, xB1;
        gload16(xA0, xp0);      gload16(xA1, xp0 + 4);
        gload16(xB0, xp0 + 32); gload16(xB1, xp0 + 36);

        STEPX(0, 2, xA0, xA1, 1, BH, BL);
        STEPX(1, 2, xB0, xB1, 1, BH, BL);
        STEPX(2, 2, xA0, xA1, 0, BH, BL);
        STEPX(3, 0, xB0, xB1, 0, BH, BL);   // vmcnt(0): W prefetch also landed

        if (ch + 1 < NCH) {
            whi[(ch + 1) & 1][e0 * 16 + cs0] = wh0;
            wlo[(ch + 1) & 1][e0 * 16 + cs0] = wl0;
            whi[(ch + 1) & 1][e1 * 16 + cs1] = wh1;
            wlo[(ch + 1) & 1][e1 * 16 + cs1] = wl1;
            __syncthreads();
        }
    }

    // atomic partial-logit accumulate (convention validated r2..r19);
    // 16 atomics/thread, 4.2M total, depth 4
#pragma unroll
    for (int n = 0; n < 4; ++n)
#pragma unroll
        for (int i = 0; i < 4; ++i) {
            const int t = wtok + grp * 4 + i;
            const int e = n * 16 + rowl;
            atomicAdd(&logits[(size_t)t * NEXP + e], acc[n][i]);
        }
}

// ---------------------------------------------------------------------------
// k2: per-thread-token bias + softmax + top-2 + scatter + counts.
// r11-validated algorithm; repackaged 256 blocks x 64 threads (2x CU
// coverage vs r19's 128x128; count-atomics 16K, still trivial).
// ---------------------------------------------------------------------------
__global__ __launch_bounds__(64)
void k2_softmax_top2(const float* __restrict__ logits, const float* __restrict__ bias,
                     float* __restrict__ out) {
    const int t = blockIdx.x * 64 + threadIdx.x;
    __shared__ float cnt[NEXP];
    __shared__ float bs[NEXP];
    cnt[threadIdx.x] = 0.f;
    bs[threadIdx.x]  = bias[threadIdx.x];
    __syncthreads();

    float l[NEXP];
    const float* lp = logits + (size_t)t * NEXP;
#pragma unroll
    for (int g = 0; g < 16; ++g) {
        float4 v = *reinterpret_cast<const float4*>(&lp[g * 4]);
        l[4 * g + 0] = v.x + bs[4 * g + 0];
        l[4 * g + 1] = v.y + bs[4 * g + 1];
        l[4 * g + 2] = v.z + bs[4 * g + 2];
        l[4 * g + 3] = v.w + bs[4 * g + 3];
    }

    float m = l[0];
#pragma unroll
    for (int e = 1; e < NEXP; ++e) m = fmaxf(m, l[e]);

    float sum = 0.f;
#pragma unroll
    for (int e = 0; e < NEXP; ++e) sum += __expf(l[e] - m);

    float v1 = -INFINITY, v2 = -INFINITY;
    int   i1 = 0, i2 = 0;
#pragma unroll
    for (int e = 0; e < NEXP; ++e) {
        if (l[e] > v1) { v2 = v1; i2 = i1; v1 = l[e]; i1 = e; }
        else if (l[e] > v2) { v2 = l[e]; i2 = e; }
    }
    const float inv = 1.f / sum;
    const float s1 = __expf(v1 - m) * inv;
    const float s2 = __expf(v2 - m) * inv;

    float* disp = out + (size_t)t * NEXP;
    float* comb = out + (size_t)NTOK * NEXP + (size_t)t * NEXP;
#pragma unroll
    for (int g = 0; g < 16; ++g) {
        float4 o = make_float4(0.f, 0.f, 0.f, 0.f);
        if ((i1 >> 2) == g) (&o.x)[i1 & 3] = s1;
        if ((i2 >> 2) == g) (&o.x)[i2 & 3] = s2;
        *reinterpret_cast<float4*>(&disp[g * 4]) = o;
        *reinterpret_cast<float4*>(&comb[g * 4]) = o;
    }

    atomicAdd(&cnt[i1], s1);
    atomicAdd(&cnt[i2], s2);
    __syncthreads();
    atomicAdd(&out[(size_t)2 * NTOK * NEXP + threadIdx.x], cnt[threadIdx.x]);
}

// ---------------------------------------------------------------------------
extern "C" void kernel_launch(void* const* d_in, const int* in_sizes, int n_in,
                              void* d_out, int out_size, void* d_ws, size_t ws_size,
                              hipStream_t stream) {
    const float* x = (const float*)d_in[0];
    const float* W = (const float*)d_in[1];
    const float* b = (const float*)d_in[2];
    float* out = (float*)d_out;
    unsigned short* ws = (unsigned short*)d_ws;          // 1 MiB W-split
    float* logits = (float*)(ws + 2 * NEXP * D_MODEL);   // + 4 MiB logit accumulator

    k0_prep<<<256, 256, 0, stream>>>(W, ws, logits, out);
    k1_gemm<<<(NTOK / BMT) * NSL, 512, 0, stream>>>(x, ws, logits);
    k2_softmax_top2<<<NTOK / 64, 64, 0, stream>>>(logits, b, out);
}

// Round 22
// 82.176 us; speedup vs baseline: 1.0399x; 1.0399x over previous
//
#include <hip/hip_runtime.h>
#include <math.h>

#define D_MODEL 4096
#define NEXP    64
#define NTOK    16384
#define NSL     4                  // K-slices; K/block = 1024
#define NCH     8                  // W-chunks per block (double-buffered)
#define KS      128                // K per LDS-resident W chunk
#define BMT     128                // tokens per block (8 waves x 16 tokens)

typedef __attribute__((ext_vector_type(8))) short  bf16x8;
typedef __attribute__((ext_vector_type(4))) float  f32x4;

__device__ __forceinline__ unsigned short f2bf_rn(float f) {
    union { float f; unsigned u; } v; v.f = f;
    unsigned r = v.u + 0x7fffu + ((v.u >> 16) & 1u);
    return (unsigned short)(r >> 16);
}
__device__ __forceinline__ float bf2f(unsigned short h) {
    union { unsigned u; float f; } v; v.u = ((unsigned)h) << 16;
    return v.f;
}
// split two floats into packed bf16 hi-word and lo-word (RNE both)
__device__ __forceinline__ void split2(float f0, float f1, unsigned& hw, unsigned& lw) {
    unsigned short h0 = f2bf_rn(f0), h1 = f2bf_rn(f1);
    unsigned short l0 = f2bf_rn(f0 - bf2f(h0)), l1 = f2bf_rn(f1 - bf2f(h1));
    hw = (unsigned)h0 | ((unsigned)h1 << 16);
    lw = (unsigned)l0 | ((unsigned)l1 << 16);
}
// pinned 16B global load (asm volatile: compiler cannot sink it to its use)
__device__ __forceinline__ void gload16(f32x4& r, const float* p) {
    asm volatile("global_load_dwordx4 %0, %1, off" : "=v"(r) : "v"(p));
}

#define WAITV_(n) asm volatile("s_waitcnt vmcnt(" #n ")" ::: "memory")
#define WAITV(n)  WAITV_(n)

// ---------------------------------------------------------------------------
// k0: split W into bf16 hi/lo halves; zero logits accumulator + counts tail.
// ---------------------------------------------------------------------------
__global__ __launch_bounds__(256)
void k0_prep(const float* __restrict__ W, unsigned short* __restrict__ ws,
             float* __restrict__ logits, float* __restrict__ out) {
    const int gid = blockIdx.x * 256 + threadIdx.x;
    if (blockIdx.x == 0 && threadIdx.x < NEXP)
        out[(size_t)2 * NTOK * NEXP + threadIdx.x] = 0.f;
    float4 z = make_float4(0.f, 0.f, 0.f, 0.f);
    float* lz = logits + (size_t)gid * 16;
#pragma unroll
    for (int k = 0; k < 4; ++k)
        *reinterpret_cast<float4*>(&lz[k * 4]) = z;
    int i = gid * 4;
    float4 v = *reinterpret_cast<const float4*>(&W[i]);
    unsigned short h[4], l[4];
    float f[4] = {v.x, v.y, v.z, v.w};
#pragma unroll
    for (int k = 0; k < 4; ++k) {
        h[k] = f2bf_rn(f[k]);
        l[k] = f2bf_rn(f[k] - bf2f(h[k]));
    }
    *reinterpret_cast<short4*>(&ws[i])                  = make_short4(h[0], h[1], h[2], h[3]);
    *reinterpret_cast<short4*>(&ws[NEXP * D_MODEL + i]) = make_short4(l[0], l[1], l[2], l[3]);
}

// ---------------------------------------------------------------------------
// k1: split-K GEMM partial — r19 exactly (83.1us validated best).
// 8 waves x 16 tokens x 64 experts, K=1024/block via 8 double-buffered
// KS=128 W chunks; W prefetch oldest-in-queue before x-prologue; pinned-asm
// x FIFO with counted vmcnt inside each chunk; __syncthreads() per chunk.
// ---------------------------------------------------------------------------
__global__ __launch_bounds__(512, 4)
void k1_gemm(const float* __restrict__ x, const unsigned short* __restrict__ wsplit,
             float* __restrict__ logits) {
    __shared__ uint4 whi[2][NEXP * 16];   // 2 x 16 KiB
    __shared__ uint4 wlo[2][NEXP * 16];   // 2 x 16 KiB

    const int tid = threadIdx.x;
    const int t0  = (blockIdx.x >> 2) * BMT;
    const int sp  = blockIdx.x & 3;    // slice -> K [sp*1024, sp*1024+1024)

    const int lane = tid & 63;
    const int rowl = lane & 15;
    const int grp  = lane >> 4;        // k-slot
    const int wtok = t0 + (tid >> 6) * 16;   // wave w -> 16-token strip

    // W staging geometry: thread covers (e,c) pairs p0=tid, p1=tid+512
    const int e0 = tid >> 4,          c0 = tid & 15;
    const int e1 = (tid + 512) >> 4,  c1 = tid & 15;   // (tid+512)&15 == tid&15
    const int cs0 = (c0 & 8) | ((c0 & 7) ^ (e0 & 7));
    const int cs1 = (c1 & 8) | ((c1 & 7) ^ (e1 & 7));

    f32x4 acc[4];
#pragma unroll
    for (int n = 0; n < 4; ++n)
        acc[n] = (f32x4){0.f, 0.f, 0.f, 0.f};

    // prologue: W chunk 0 -> buf 0 (the single serial W phase)
    {
        const int ks00 = sp * (NCH * KS);
        const unsigned short* s0 = wsplit + (size_t)e0 * D_MODEL + ks00 + c0 * 8;
        const unsigned short* s1 = wsplit + (size_t)e1 * D_MODEL + ks00 + c1 * 8;
        whi[0][e0 * 16 + cs0] = *reinterpret_cast<const uint4*>(s0);
        wlo[0][e0 * 16 + cs0] = *reinterpret_cast<const uint4*>(s0 + NEXP * D_MODEL);
        whi[0][e1 * 16 + cs1] = *reinterpret_cast<const uint4*>(s1);
        wlo[0][e1 * 16 + cs1] = *reinterpret_cast<const uint4*>(s1 + NEXP * D_MODEL);
    }
    __syncthreads();

// one pipeline step: wait iter-kb, split, re-issue regs for iter kb+2, MFMA
#define STEPX(kb, WN, c0r, c1r, DOI, BH, BL) do {                            \
    WAITV(WN);                                                               \
    __builtin_amdgcn_sched_barrier(0);                                       \
    union { bf16x8 v; unsigned u[4]; } ah, al;                               \
    split2(c0r.x, c0r.y, ah.u[0], al.u[0]);                                  \
    split2(c0r.z, c0r.w, ah.u[1], al.u[1]);                                  \
    split2(c1r.x, c1r.y, ah.u[2], al.u[2]);                                  \
    split2(c1r.z, c1r.w, ah.u[3], al.u[3]);                                  \
    if (DOI) {                                                               \
        gload16(c0r, xp0 + ((kb) + 2) * 32);                                 \
        gload16(c1r, xp0 + ((kb) + 2) * 32 + 4);                             \
    }                                                                        \
    const int c  = (kb) * 4 + grp;                                           \
    const int cs = (c & 8) | ((c & 7) ^ (rowl & 7));    /* e&7 == rowl&7 */  \
    _Pragma("unroll")                                                        \
    for (int n = 0; n < 4; ++n) {                                            \
        const int idx = (n * 16 + rowl) * 16 + cs;                           \
        bf16x8 bh = *reinterpret_cast<const bf16x8*>(&BH[idx]);              \
        bf16x8 bl = *reinterpret_cast<const bf16x8*>(&BL[idx]);              \
        acc[n] = __builtin_amdgcn_mfma_f32_16x16x32_bf16(ah.v, bh, acc[n], 0, 0, 0); \
        acc[n] = __builtin_amdgcn_mfma_f32_16x16x32_bf16(ah.v, bl, acc[n], 0, 0, 0); \
        acc[n] = __builtin_amdgcn_mfma_f32_16x16x32_bf16(al.v, bh, acc[n], 0, 0, 0); \
    }                                                                        \
} while (0)

#pragma unroll
    for (int ch = 0; ch < NCH; ++ch) {
        const int ks0 = sp * (NCH * KS) + ch * KS;

        // prefetch next W chunk into regs FIRST (oldest in vmcnt queue);
        // sched_barrier pins against sinking (r4 pathology)
        uint4 wh0, wl0, wh1, wl1;
        if (ch + 1 < NCH) {
            const unsigned short* s0 = wsplit + (size_t)e0 * D_MODEL + ks0 + KS + c0 * 8;
            const unsigned short* s1 = wsplit + (size_t)e1 * D_MODEL + ks0 + KS + c1 * 8;
            wh0 = *reinterpret_cast<const uint4*>(s0);
            wl0 = *reinterpret_cast<const uint4*>(s0 + NEXP * D_MODEL);
            wh1 = *reinterpret_cast<const uint4*>(s1);
            wl1 = *reinterpret_cast<const uint4*>(s1 + NEXP * D_MODEL);
        }
        __builtin_amdgcn_sched_barrier(0);

        const uint4* BH = &whi[ch & 1][0];
        const uint4* BL = &wlo[ch & 1][0];
        const float* xp0 = x + (size_t)(wtok + rowl) * D_MODEL + ks0 + grp * 8;

        // x prologue: pin iters 0 (A) and 1 (B) in flight
        f32x4 xA0, xA1, xB0, xB1;
        gload16(xA0, xp0);      gload16(xA1, xp0 + 4);
        gload16(xB0, xp0 + 32); gload16(xB1, xp0 + 36);

        STEPX(0, 2, xA0, xA1, 1, BH, BL);
        STEPX(1, 2, xB0, xB1, 1, BH, BL);
        STEPX(2, 2, xA0, xA1, 0, BH, BL);
        STEPX(3, 0, xB0, xB1, 0, BH, BL);   // vmcnt(0): W prefetch also landed

        if (ch + 1 < NCH) {
            whi[(ch + 1) & 1][e0 * 16 + cs0] = wh0;
            wlo[(ch + 1) & 1][e0 * 16 + cs0] = wl0;
            whi[(ch + 1) & 1][e1 * 16 + cs1] = wh1;
            wlo[(ch + 1) & 1][e1 * 16 + cs1] = wl1;
            __syncthreads();
        }
    }

    // atomic partial-logit accumulate (convention validated r2..r19);
    // 16 atomics/thread, 4.2M total, depth 4
#pragma unroll
    for (int n = 0; n < 4; ++n)
#pragma unroll
        for (int i = 0; i < 4; ++i) {
            const int t = wtok + grp * 4 + i;
            const int e = n * 16 + rowl;
            atomicAdd(&logits[(size_t)t * NEXP + e], acc[n][i]);
        }
}

// ---------------------------------------------------------------------------
// k2: per-thread-token bias + softmax + top-2 + scatter + counts
// (r11/r19-validated, byte-identical: 128 blocks x 128 threads).
// ---------------------------------------------------------------------------
__global__ __launch_bounds__(128)
void k2_softmax_top2(const float* __restrict__ logits, const float* __restrict__ bias,
                     float* __restrict__ out) {
    const int t = blockIdx.x * 128 + threadIdx.x;
    __shared__ float cnt[NEXP];
    __shared__ float bs[NEXP];
    if (threadIdx.x < NEXP) {
        cnt[threadIdx.x] = 0.f;
        bs[threadIdx.x]  = bias[threadIdx.x];
    }
    __syncthreads();

    float l[NEXP];
    const float* lp = logits + (size_t)t * NEXP;
#pragma unroll
    for (int g = 0; g < 16; ++g) {
        float4 v = *reinterpret_cast<const float4*>(&lp[g * 4]);
        l[4 * g + 0] = v.x + bs[4 * g + 0];
        l[4 * g + 1] = v.y + bs[4 * g + 1];
        l[4 * g + 2] = v.z + bs[4 * g + 2];
        l[4 * g + 3] = v.w + bs[4 * g + 3];
    }

    float m = l[0];
#pragma unroll
    for (int e = 1; e < NEXP; ++e) m = fmaxf(m, l[e]);

    float sum = 0.f;
#pragma unroll
    for (int e = 0; e < NEXP; ++e) sum += __expf(l[e] - m);

    float v1 = -INFINITY, v2 = -INFINITY;
    int   i1 = 0, i2 = 0;
#pragma unroll
    for (int e = 0; e < NEXP; ++e) {
        if (l[e] > v1) { v2 = v1; i2 = i1; v1 = l[e]; i1 = e; }
        else if (l[e] > v2) { v2 = l[e]; i2 = e; }
    }
    const float inv = 1.f / sum;
    const float s1 = __expf(v1 - m) * inv;
    const float s2 = __expf(v2 - m) * inv;

    float* disp = out + (size_t)t * NEXP;
    float* comb = out + (size_t)NTOK * NEXP + (size_t)t * NEXP;
#pragma unroll
    for (int g = 0; g < 16; ++g) {
        float4 o = make_float4(0.f, 0.f, 0.f, 0.f);
        if ((i1 >> 2) == g) (&o.x)[i1 & 3] = s1;
        if ((i2 >> 2) == g) (&o.x)[i2 & 3] = s2;
        *reinterpret_cast<float4*>(&disp[g * 4]) = o;
        *reinterpret_cast<float4*>(&comb[g * 4]) = o;
    }

    atomicAdd(&cnt[i1], s1);
    atomicAdd(&cnt[i2], s2);
    __syncthreads();
    if (threadIdx.x < NEXP)
        atomicAdd(&out[(size_t)2 * NTOK * NEXP + threadIdx.x], cnt[threadIdx.x]);
}

// ---------------------------------------------------------------------------
extern "C" void kernel_launch(void* const* d_in, const int* in_sizes, int n_in,
                              void* d_out, int out_size, void* d_ws, size_t ws_size,
                              hipStream_t stream) {
    const float* x = (const float*)d_in[0];
    const float* W = (const float*)d_in[1];
    const float* b = (const float*)d_in[2];
    float* out = (float*)d_out;
    unsigned short* ws = (unsigned short*)d_ws;          // 1 MiB W-split
    float* logits = (float*)(ws + 2 * NEXP * D_MODEL);   // + 4 MiB logit accumulator

    k0_prep<<<256, 256, 0, stream>>>(W, ws, logits, out);
    k1_gemm<<<(NTOK / BMT) * NSL, 512, 0, stream>>>(x, ws, logits);
    k2_softmax_top2<<<NTOK / 128, 128, 0, stream>>>(logits, b, out);
}